// Round 14
// baseline (49.664 us; speedup 1.0000x reference)
//
#include <hip/hip_runtime.h>
#include <hip/hip_bf16.h>

// SpatialAttention2D MFMA v13: B=2, C=64, N=4096, 4 heads x d=16, fp32 io.
// vs v12(best,41.3): attn reverted to the r12 structure (32q/wave, depth-2
// register pipeline, 4 key-quarter waves). qkv rewritten TOKEN-PARALLEL:
// lane = token, wave = (part,head). All x loads and Q/K stores coalesced
// (thread owns all 16 d of its token -> 32B contiguous); w rows are
// wave-uniform L1-broadcast loads. Q now stored [n][d] (attn reads qf as
// one b64 vector load). K [n][d] and V frag-ordered unchanged.

#define NTOK 4096
#define HD   16
#define BH   8
#define QUART 1024             // keys per wave (key-quarter)
#define PITERS (QUART/32)      // 32 pair-iters (2 chunks of 16 keys each)

typedef __attribute__((ext_vector_type(4))) short short4v;
typedef __attribute__((ext_vector_type(4))) float float4v;
typedef __attribute__((ext_vector_type(4))) ushort ushort4v;
typedef __attribute__((ext_vector_type(2))) unsigned uint2v;

__device__ __forceinline__ ushort f2bf(float f) {
  unsigned u = __builtin_bit_cast(unsigned, f);
  u += 0x7fffu + ((u >> 16) & 1u);          // round-to-nearest-even
  return (ushort)(u >> 16);
}

__device__ __forceinline__ float fast_exp2(float x) {
#if __has_builtin(__builtin_amdgcn_exp2f)
  return __builtin_amdgcn_exp2f(x);
#else
  return exp2f(x);
#endif
}

// packed f32x4 -> bf16x4 (RNE) via v_cvt_pk_bf16_f32 (v6b-verified form)
__device__ __forceinline__ short4v pack4_bf16(float a, float b, float c, float d) {
  __hip_bfloat162 lo = __float22bfloat162_rn(make_float2(a, b));
  __hip_bfloat162 hi = __float22bfloat162_rn(make_float2(c, d));
  unsigned ulo, uhi;
  __builtin_memcpy(&ulo, &lo, 4);
  __builtin_memcpy(&uhi, &hi, 4);
  uint2v u = { ulo, uhi };
  return __builtin_bit_cast(short4v, u);
}

// ws layout in ushort elements (3 MB total)
// Qb: [bh][n][d], Kb: [bh][n][d], Vf: [bh] fragment-ordered:
//   element (d, key) at bh*65536 + (key>>4)*256 + ((key&15)>>2)*64 + d*4 + (key&3)
#define QB_OFF 0
#define KB_OFF ((size_t)BH*NTOK*HD)
#define VT_OFF (2*(size_t)BH*NTOK*HD)

// ---------------------------------------------------------------------------
// Kernel 1: QKV projection, token-parallel. Grid = 128 token-groups x 3
// combo-groups = 384 blocks x 256 threads. Wave wid -> combo = cg*4+wid =
// (part, head); lane = token. 64 x-values in VGPRs; w rows wave-uniform.
// q scaled by 0.25*log2(e). Q,K stored [n][d] coalesced; V frag-ordered.
// ---------------------------------------------------------------------------
__global__ __launch_bounds__(256) void qkv_proj(
    const float* __restrict__ x, const float* __restrict__ w,
    const float* __restrict__ bias, ushort* __restrict__ wsu) {
  int tg   = blockIdx.x / 3;       // 0..127: token group (64 tokens)
  int cg   = blockIdx.x % 3;       // combo group
  int wid  = threadIdx.x >> 6;
  int lane = threadIdx.x & 63;
  int combo = cg*4 + wid;          // 0..11
  int part = combo >> 2;           // 0=q,1=k,2=v
  int h    = combo & 3;
  int b    = tg >> 6;
  int np   = (tg & 63)*64 + lane;  // token within batch
  int bh   = b*4 + h;
  const float QSCALE = 0.25f * 1.44269504f;

  // x column for this token: 64 coalesced loads (lane = np contiguous)
  float xr[64];
  const float* xp = x + (size_t)b*64*NTOK + np;
  #pragma unroll
  for (int c = 0; c < 64; ++c)
    xr[c] = xp[(size_t)c*NTOK];

  const float* wp = w + (size_t)(part*64 + h*16)*64;   // 16 rows, wave-uniform
  const float* bp = bias + part*64 + h*16;

  unsigned res[8];                 // 16 bf16 results packed

  #pragma unroll
  for (int oo = 0; oo < 16; ++oo) {
    const float4* w4 = reinterpret_cast<const float4*>(wp + oo*64);
    float acc = bp[oo];
    #pragma unroll
    for (int i = 0; i < 16; ++i) {
      float4 wv = w4[i];
      acc = fmaf(xr[4*i+0], wv.x, acc);
      acc = fmaf(xr[4*i+1], wv.y, acc);
      acc = fmaf(xr[4*i+2], wv.z, acc);
      acc = fmaf(xr[4*i+3], wv.w, acc);
    }
    float val = (part == 0) ? acc*QSCALE : acc;
    unsigned u = f2bf(val);
    if ((oo & 1) == 0) res[oo >> 1] = u;
    else               res[oo >> 1] |= (u << 16);
  }

  ushort* Qb = wsu + QB_OFF;
  ushort* Kb = wsu + KB_OFF;
  ushort* Vf = wsu + VT_OFF;

  if (part == 0) {                 // Q [n][d]: 32B contiguous per thread
    uint4* dst = (uint4*)(Qb + ((size_t)bh*NTOK + np)*HD);
    dst[0] = make_uint4(res[0], res[1], res[2], res[3]);
    dst[1] = make_uint4(res[4], res[5], res[6], res[7]);
  } else if (part == 1) {          // K [n][d]: 32B contiguous per thread
    uint4* dst = (uint4*)(Kb + ((size_t)bh*NTOK + np)*HD);
    dst[0] = make_uint4(res[0], res[1], res[2], res[3]);
    dst[1] = make_uint4(res[4], res[5], res[6], res[7]);
  } else {                         // V fragment-ordered: 16 scalar stores
    ushort* vb = Vf + (size_t)bh*NTOK*HD
               + (np >> 4)*256 + ((np & 15) >> 2)*64 + (np & 3);
    #pragma unroll
    for (int d = 0; d < 16; ++d)
      vb[d*4] = (ushort)(res[d >> 1] >> ((d & 1)*16));
  }
}

// ---------------------------------------------------------------------------
// Kernel 2: register-direct MFMA flash attention (r12 structure, byte-equal
// except Q-frag load from [n][d] as one b64 vector read per frag).
// Grid = 8 bh x 128 qblk(32q) = 1024 blocks x 256 threads (4 waves).
// Wave = key-quarter; all 4 waves cover the SAME 32 q. All frag loads are
// coalesced 512B/wave. Depth-2 pipeline; epilogue combines via small LDS.
// ---------------------------------------------------------------------------
__global__ __launch_bounds__(256, 4) void attn_mfma(
    const ushort* __restrict__ wsu, float* __restrict__ out) {
  const ushort* Qt = wsu + QB_OFF;
  const ushort* Kb = wsu + KB_OFF;
  const ushort* Vt = wsu + VT_OFF;

  int bh    = blockIdx.x >> 7;
  int qblk  = blockIdx.x & 127;
  int tid   = threadIdx.x;
  int quart = tid >> 6;            // 0..3: key-quarter
  int lane  = tid & 63;
  int lr    = lane & 15;
  int g4    = (lane >> 4) << 2;
  int qbase = qblk*32;

  __shared__ float comb[3][64][11];   // 8.4 KB epilogue combine

  const ushort* Qh = Qt + (size_t)bh*NTOK*HD;                       // [n][d]
  const ushort* Kh = Kb + ((size_t)bh*NTOK + (size_t)quart*QUART)*HD;
  const ushort* Vh = Vt + (size_t)bh*NTOK*HD + (size_t)quart*QUART*HD;

  // Q fragments (B operand): lane l holds Q[q][d=g4..g4+3], q-groups 0/1
  short4v qf0 = *(const short4v*)(Qh + (size_t)(qbase      + lr)*HD + g4);
  short4v qf1 = *(const short4v*)(Qh + (size_t)(qbase + 16 + lr)*HD + g4);

  // per-lane fragment pointers (ushort units); iter i reads at i*512 (+256)
  const ushort* kp = Kh + lr*HD + (lane >> 4)*4;
  const ushort* vp = Vh + lane*4;

  float4v a0e = {0.f,0.f,0.f,0.f}, a0o = {0.f,0.f,0.f,0.f};
  float4v a1e = {0.f,0.f,0.f,0.f}, a1o = {0.f,0.f,0.f,0.f};
  float l0 = 0.f, l1 = 0.f;

#define ITER(ke, ko, ve, vo)                                                \
  do {                                                                      \
    float4v zero = {0.f,0.f,0.f,0.f};                                       \
    __builtin_amdgcn_s_setprio(1);                                          \
    float4v s0e = __builtin_amdgcn_mfma_f32_16x16x16bf16_1k(ke, qf0, zero, 0,0,0); \
    float4v s0o = __builtin_amdgcn_mfma_f32_16x16x16bf16_1k(ko, qf0, zero, 0,0,0); \
    float4v s1e = __builtin_amdgcn_mfma_f32_16x16x16bf16_1k(ke, qf1, zero, 0,0,0); \
    float4v s1o = __builtin_amdgcn_mfma_f32_16x16x16bf16_1k(ko, qf1, zero, 0,0,0); \
    float p0e0 = fast_exp2(s0e[0]), p0e1 = fast_exp2(s0e[1]);               \
    float p0e2 = fast_exp2(s0e[2]), p0e3 = fast_exp2(s0e[3]);               \
    float p0o0 = fast_exp2(s0o[0]), p0o1 = fast_exp2(s0o[1]);               \
    float p0o2 = fast_exp2(s0o[2]), p0o3 = fast_exp2(s0o[3]);               \
    float p1e0 = fast_exp2(s1e[0]), p1e1 = fast_exp2(s1e[1]);               \
    float p1e2 = fast_exp2(s1e[2]), p1e3 = fast_exp2(s1e[3]);               \
    float p1o0 = fast_exp2(s1o[0]), p1o1 = fast_exp2(s1o[1]);               \
    float p1o2 = fast_exp2(s1o[2]), p1o3 = fast_exp2(s1o[3]);               \
    l0 += (p0e0 + p0e1) + (p0e2 + p0e3) + (p0o0 + p0o1) + (p0o2 + p0o3);    \
    l1 += (p1e0 + p1e1) + (p1e2 + p1e3) + (p1o0 + p1o1) + (p1o2 + p1o3);    \
    short4v pb0e = pack4_bf16(p0e0, p0e1, p0e2, p0e3);                      \
    short4v pb0o = pack4_bf16(p0o0, p0o1, p0o2, p0o3);                      \
    short4v pb1e = pack4_bf16(p1e0, p1e1, p1e2, p1e3);                      \
    short4v pb1o = pack4_bf16(p1o0, p1o1, p1o2, p1o3);                      \
    a0e = __builtin_amdgcn_mfma_f32_16x16x16bf16_1k(ve, pb0e, a0e, 0,0,0);  \
    a0o = __builtin_amdgcn_mfma_f32_16x16x16bf16_1k(vo, pb0o, a0o, 0,0,0);  \
    a1e = __builtin_amdgcn_mfma_f32_16x16x16bf16_1k(ve, pb1e, a1e, 0,0,0);  \
    a1o = __builtin_amdgcn_mfma_f32_16x16x16bf16_1k(vo, pb1o, a1o, 0,0,0);  \
    __builtin_amdgcn_s_setprio(0);                                          \
  } while (0)

  // prologue: fragments for iters 0 (A) and 1 (B)
  short4v kAe = *(const short4v*)(kp);
  short4v kAo = *(const short4v*)(kp + 256);
  short4v vAe = *(const short4v*)(vp);
  short4v vAo = *(const short4v*)(vp + 256);
  short4v kBe = *(const short4v*)(kp + 512);
  short4v kBo = *(const short4v*)(kp + 768);
  short4v vBe = *(const short4v*)(vp + 512);
  short4v vBo = *(const short4v*)(vp + 768);

  #pragma unroll 4
  for (int it2 = 0; it2 < PITERS/2; ++it2) {
    // prefetch iters 2*it2+2 (A') and 2*it2+3 (B'); benign ws over-read at tail
    int oA = (2*it2 + 2) * 512;
    int oB = (2*it2 + 3) * 512;
    short4v nkAe = *(const short4v*)(kp + oA);
    short4v nkAo = *(const short4v*)(kp + oA + 256);
    short4v nvAe = *(const short4v*)(vp + oA);
    short4v nvAo = *(const short4v*)(vp + oA + 256);
    short4v nkBe = *(const short4v*)(kp + oB);
    short4v nkBo = *(const short4v*)(kp + oB + 256);
    short4v nvBe = *(const short4v*)(vp + oB);
    short4v nvBo = *(const short4v*)(vp + oB + 256);

    ITER(kAe, kAo, vAe, vAo);
    ITER(kBe, kBo, vBe, vBo);

    kAe = nkAe; kAo = nkAo; vAe = nvAe; vAo = nvAo;
    kBe = nkBe; kBo = nkBo; vBe = nvBe; vBo = nvBo;
  }
#undef ITER

  // per-wave partial outputs (key-quarter partials)
  float o0[4], o1[4];
  #pragma unroll
  for (int r = 0; r < 4; ++r) {
    o0[r] = a0e[r] + a0o[r];
    o1[r] = a1e[r] + a1o[r];
  }

  // combine the 4 quarters: waves 1..3 publish, wave 0 reduces + stores
  if (quart != 0) {
    float* cp = &comb[quart-1][lane][0];
    cp[0] = o0[0]; cp[1] = o0[1]; cp[2] = o0[2]; cp[3] = o0[3];
    cp[4] = o1[0]; cp[5] = o1[1]; cp[6] = o1[2]; cp[7] = o1[3];
    cp[8] = l0;    cp[9] = l1;
  }
  __syncthreads();
  if (quart == 0) {
    #pragma unroll
    for (int wv = 0; wv < 3; ++wv) {
      const float* cp = &comb[wv][lane][0];
      o0[0] += cp[0]; o0[1] += cp[1]; o0[2] += cp[2]; o0[3] += cp[3];
      o1[0] += cp[4]; o1[1] += cp[5]; o1[2] += cp[6]; o1[3] += cp[7];
      l0 += cp[8];    l1 += cp[9];
    }
    // total l per q (lanes l^16, l^32 hold the same q)
    l0 += __shfl_xor(l0, 16); l0 += __shfl_xor(l0, 32);
    l1 += __shfl_xor(l1, 16); l1 += __shfl_xor(l1, 32);
    float inv0 = 1.0f / l0, inv1 = 1.0f / l1;

    int b = bh >> 2, h = bh & 3;
    float* ob = out + ((size_t)(b*64 + h*16 + g4)) * NTOK;
    #pragma unroll
    for (int r = 0; r < 4; ++r) {
      ob[(size_t)r*NTOK + qbase      + lr] = o0[r] * inv0;
      ob[(size_t)r*NTOK + qbase + 16 + lr] = o1[r] * inv1;
    }
  }
}

extern "C" void kernel_launch(void* const* d_in, const int* in_sizes, int n_in,
                              void* d_out, int out_size, void* d_ws, size_t ws_size,
                              hipStream_t stream) {
  const float* x    = (const float*)d_in[0];   // (2,64,64,64)
  const float* w    = (const float*)d_in[1];   // (192,64)
  const float* bias = (const float*)d_in[2];   // (192,)
  float* out  = (float*)d_out;                 // (2,64,64,64)
  ushort* wsu = (ushort*)d_ws;                 // 3 MB used (+2KB over-read pad)

  qkv_proj <<<384,  256, 0, stream>>>(x, w, bias, wsu);
  attn_mfma<<<1024, 256, 0, stream>>>(wsu, out);
}

// Round 15
// 41.765 us; speedup vs baseline: 1.1891x; 1.1891x over previous
//
#include <hip/hip_runtime.h>
#include <hip/hip_bf16.h>

// SpatialAttention2D MFMA v14: B=2, C=64, N=4096, 4 heads x d=16, fp32 io.
// vs v12(best,41.3): qkv reverted to the r12-proven kernel byte-for-byte.
// attn: (1) s_setprio pairs REMOVED from the inner loop (they fenced the
// scheduler at every ITER, blocking cross-iter interleave of exp/pack with
// neighbor-iter MFMAs); (2) 8 key-eighth waves per 512-thr block
// (launch_bounds(512,6), ~84 VGPR cap) -> 6 waves/SIMD for stall coverage.
// Same total wave-iters and L2 traffic as v12; epilogue combines 8 partials.

#define NTOK 4096
#define HD   16
#define BH   8
#define EIGHTH 512             // keys per wave (key-eighth)
#define PITERS (EIGHTH/32)     // 16 pair-iters (2 chunks of 16 keys each)

typedef __attribute__((ext_vector_type(4))) short short4v;
typedef __attribute__((ext_vector_type(4))) float float4v;
typedef __attribute__((ext_vector_type(4))) ushort ushort4v;
typedef __attribute__((ext_vector_type(2))) unsigned uint2v;

__device__ __forceinline__ ushort f2bf(float f) {
  unsigned u = __builtin_bit_cast(unsigned, f);
  u += 0x7fffu + ((u >> 16) & 1u);          // round-to-nearest-even
  return (ushort)(u >> 16);
}

__device__ __forceinline__ float fast_exp2(float x) {
#if __has_builtin(__builtin_amdgcn_exp2f)
  return __builtin_amdgcn_exp2f(x);
#else
  return exp2f(x);
#endif
}

// packed f32x4 -> bf16x4 (RNE) via v_cvt_pk_bf16_f32 (v6b-verified form)
__device__ __forceinline__ short4v pack4_bf16(float a, float b, float c, float d) {
  __hip_bfloat162 lo = __float22bfloat162_rn(make_float2(a, b));
  __hip_bfloat162 hi = __float22bfloat162_rn(make_float2(c, d));
  unsigned ulo, uhi;
  __builtin_memcpy(&ulo, &lo, 4);
  __builtin_memcpy(&uhi, &hi, 4);
  uint2v u = { ulo, uhi };
  return __builtin_bit_cast(short4v, u);
}

// ws layout in ushort elements (3 MB total)
// Qt: [bh][d][n] (transposed), Kb: [bh][n][d], Vf: [bh] fragment-ordered:
//   element (d, key) at bh*65536 + (key>>4)*256 + ((key&15)>>2)*64 + d*4 + (key&3)
#define QB_OFF 0
#define KB_OFF ((size_t)BH*NTOK*HD)
#define VT_OFF (2*(size_t)BH*NTOK*HD)

// ---------------------------------------------------------------------------
// Kernel 1: QKV projection (byte-identical to r12's proven kernel).
// ---------------------------------------------------------------------------
__global__ __launch_bounds__(192) void qkv_proj(
    const float* __restrict__ x, const float* __restrict__ w,
    const float* __restrict__ bias, ushort* __restrict__ wsu) {
  const int TOK = 8, TILES = 2;
  int blk = blockIdx.x;            // 512
  int b   = blk >> 8;
  int n00 = (blk & 255) * (TOK*TILES);
  int o   = threadIdx.x;           // 0..191

  float wr[64];
  const float4* w4 = reinterpret_cast<const float4*>(w + o*64);
  #pragma unroll
  for (int i = 0; i < 16; ++i) {
    float4 tt = w4[i];
    wr[4*i+0]=tt.x; wr[4*i+1]=tt.y; wr[4*i+2]=tt.z; wr[4*i+3]=tt.w;
  }
  float bb = bias[o];

  int part = o >> 6;               // 0=q,1=k,2=v
  int oo   = o & 63;
  int h    = oo >> 4;
  int dd   = oo & 15;
  int bh   = b*4 + h;
  const float QSCALE = 0.25f * 1.44269504f;

  ushort* Qt = wsu + QB_OFF;
  ushort* Kb = wsu + KB_OFF;
  ushort* Vf = wsu + VT_OFF;

  __shared__ float4 xs4[64][2];
  const float4* x4 = reinterpret_cast<const float4*>(x);

  #pragma unroll 1
  for (int tile = 0; tile < TILES; ++tile) {
    int n0 = n00 + tile*TOK;
    for (int idx = threadIdx.x; idx < 128; idx += 192) {
      int c = idx >> 1, t4 = idx & 1;
      xs4[c][t4] = x4[((size_t)b*64 + c)*(NTOK/4) + (n0 >> 2) + t4];
    }
    __syncthreads();

    #pragma unroll
    for (int t4 = 0; t4 < 2; ++t4) {
      float a[4] = {bb, bb, bb, bb};
      #pragma unroll
      for (int c = 0; c < 64; ++c) {
        float4 xv = xs4[c][t4];
        float wv = wr[c];
        a[0] = fmaf(xv.x, wv, a[0]);
        a[1] = fmaf(xv.y, wv, a[1]);
        a[2] = fmaf(xv.z, wv, a[2]);
        a[3] = fmaf(xv.w, wv, a[3]);
      }
      if (part == 0) {
        ushort4v vv = { f2bf(a[0]*QSCALE), f2bf(a[1]*QSCALE),
                        f2bf(a[2]*QSCALE), f2bf(a[3]*QSCALE) };
        *(ushort4v*)(Qt + ((size_t)bh*HD + dd)*NTOK + n0 + t4*4) = vv;
      } else if (part == 1) {
        #pragma unroll
        for (int j = 0; j < 4; ++j)
          Kb[((size_t)bh*NTOK + n0 + t4*4 + j)*HD + dd] = f2bf(a[j]);
      } else {
        int m = n0 + t4*4;
        size_t idx = (size_t)bh*NTOK*HD + (m >> 4)*256 + ((m & 15) >> 2)*64 + dd*4;
        ushort4v vv = { f2bf(a[0]), f2bf(a[1]), f2bf(a[2]), f2bf(a[3]) };
        *(ushort4v*)(Vf + idx) = vv;
      }
    }
    __syncthreads();
  }
}

// ---------------------------------------------------------------------------
// Kernel 2: register-direct MFMA flash attention, 8 key-eighth waves.
// Grid = 8 bh x 128 qblk(32q) = 1024 blocks x 512 threads (8 waves).
// Wave wid = key-eighth (512 keys); all 8 waves cover the SAME 32 q.
// Depth-2 register pipeline (r12-verified addressing), NO setprio fences.
// Epilogue: waves 1..7 publish partials to LDS, wave 0 combines + stores.
// ---------------------------------------------------------------------------
__global__ __launch_bounds__(512, 6) void attn_mfma(
    const ushort* __restrict__ wsu, float* __restrict__ out) {
  const ushort* Qt = wsu + QB_OFF;
  const ushort* Kb = wsu + KB_OFF;
  const ushort* Vt = wsu + VT_OFF;

  int bh   = blockIdx.x >> 7;
  int qblk = blockIdx.x & 127;
  int tid  = threadIdx.x;
  int wid  = tid >> 6;             // 0..7: key-eighth
  int lane = tid & 63;
  int lr   = lane & 15;
  int g4   = (lane >> 4) << 2;
  int qbase = qblk*32;

  __shared__ float comb[7][64][10];   // 17.9 KB epilogue combine

  const ushort* Qh = Qt + (size_t)bh*HD*NTOK;                       // [d][n]
  const ushort* Kh = Kb + ((size_t)bh*NTOK + (size_t)wid*EIGHTH)*HD;
  const ushort* Vh = Vt + (size_t)bh*NTOK*HD + (size_t)wid*EIGHTH*HD;

  // Q fragments (B operand): lane l holds Q[q][d=g4..g4+3], q-groups 0/1
  short4v qf0, qf1;
  #pragma unroll
  for (int j = 0; j < 4; ++j) {
    qf0[j] = (short)Qh[(size_t)(g4+j)*NTOK + qbase      + lr];
    qf1[j] = (short)Qh[(size_t)(g4+j)*NTOK + qbase + 16 + lr];
  }

  // per-lane fragment pointers (ushort units); pair-iter i reads i*512 (+256)
  const ushort* kp = Kh + lr*HD + (lane >> 4)*4;
  const ushort* vp = Vh + lane*4;

  float4v a0e = {0.f,0.f,0.f,0.f}, a0o = {0.f,0.f,0.f,0.f};
  float4v a1e = {0.f,0.f,0.f,0.f}, a1o = {0.f,0.f,0.f,0.f};
  float l0 = 0.f, l1 = 0.f;

#define ITER(ke, ko, ve, vo)                                                \
  do {                                                                      \
    float4v zero = {0.f,0.f,0.f,0.f};                                       \
    float4v s0e = __builtin_amdgcn_mfma_f32_16x16x16bf16_1k(ke, qf0, zero, 0,0,0); \
    float4v s0o = __builtin_amdgcn_mfma_f32_16x16x16bf16_1k(ko, qf0, zero, 0,0,0); \
    float4v s1e = __builtin_amdgcn_mfma_f32_16x16x16bf16_1k(ke, qf1, zero, 0,0,0); \
    float4v s1o = __builtin_amdgcn_mfma_f32_16x16x16bf16_1k(ko, qf1, zero, 0,0,0); \
    float p0e0 = fast_exp2(s0e[0]), p0e1 = fast_exp2(s0e[1]);               \
    float p0e2 = fast_exp2(s0e[2]), p0e3 = fast_exp2(s0e[3]);               \
    float p0o0 = fast_exp2(s0o[0]), p0o1 = fast_exp2(s0o[1]);               \
    float p0o2 = fast_exp2(s0o[2]), p0o3 = fast_exp2(s0o[3]);               \
    float p1e0 = fast_exp2(s1e[0]), p1e1 = fast_exp2(s1e[1]);               \
    float p1e2 = fast_exp2(s1e[2]), p1e3 = fast_exp2(s1e[3]);               \
    float p1o0 = fast_exp2(s1o[0]), p1o1 = fast_exp2(s1o[1]);               \
    float p1o2 = fast_exp2(s1o[2]), p1o3 = fast_exp2(s1o[3]);               \
    l0 += (p0e0 + p0e1) + (p0e2 + p0e3) + (p0o0 + p0o1) + (p0o2 + p0o3);    \
    l1 += (p1e0 + p1e1) + (p1e2 + p1e3) + (p1o0 + p1o1) + (p1o2 + p1o3);    \
    short4v pb0e = pack4_bf16(p0e0, p0e1, p0e2, p0e3);                      \
    short4v pb0o = pack4_bf16(p0o0, p0o1, p0o2, p0o3);                      \
    short4v pb1e = pack4_bf16(p1e0, p1e1, p1e2, p1e3);                      \
    short4v pb1o = pack4_bf16(p1o0, p1o1, p1o2, p1o3);                      \
    a0e = __builtin_amdgcn_mfma_f32_16x16x16bf16_1k(ve, pb0e, a0e, 0,0,0);  \
    a0o = __builtin_amdgcn_mfma_f32_16x16x16bf16_1k(vo, pb0o, a0o, 0,0,0);  \
    a1e = __builtin_amdgcn_mfma_f32_16x16x16bf16_1k(ve, pb1e, a1e, 0,0,0);  \
    a1o = __builtin_amdgcn_mfma_f32_16x16x16bf16_1k(vo, pb1o, a1o, 0,0,0);  \
  } while (0)

  // prologue: fragments for pair-iters 0 (A) and 1 (B)
  short4v kAe = *(const short4v*)(kp);
  short4v kAo = *(const short4v*)(kp + 256);
  short4v vAe = *(const short4v*)(vp);
  short4v vAo = *(const short4v*)(vp + 256);
  short4v kBe = *(const short4v*)(kp + 512);
  short4v kBo = *(const short4v*)(kp + 768);
  short4v vBe = *(const short4v*)(vp + 512);
  short4v vBo = *(const short4v*)(vp + 768);

  #pragma unroll 4
  for (int it2 = 0; it2 < PITERS/2; ++it2) {
    // prefetch pair-iters 2*it2+2 / 2*it2+3 (benign ws over-read at tail)
    int oA = (2*it2 + 2) * 512;
    int oB = (2*it2 + 3) * 512;
    short4v nkAe = *(const short4v*)(kp + oA);
    short4v nkAo = *(const short4v*)(kp + oA + 256);
    short4v nvAe = *(const short4v*)(vp + oA);
    short4v nvAo = *(const short4v*)(vp + oA + 256);
    short4v nkBe = *(const short4v*)(kp + oB);
    short4v nkBo = *(const short4v*)(kp + oB + 256);
    short4v nvBe = *(const short4v*)(vp + oB);
    short4v nvBo = *(const short4v*)(vp + oB + 256);

    ITER(kAe, kAo, vAe, vAo);
    ITER(kBe, kBo, vBe, vBo);

    kAe = nkAe; kAo = nkAo; vAe = nvAe; vAo = nvAo;
    kBe = nkBe; kBo = nkBo; vBe = nvBe; vBo = nvBo;
  }
#undef ITER

  // per-wave partial outputs (key-eighth partials)
  float o0[4], o1[4];
  #pragma unroll
  for (int r = 0; r < 4; ++r) {
    o0[r] = a0e[r] + a0o[r];
    o1[r] = a1e[r] + a1o[r];
  }

  // combine the 8 eighths: waves 1..7 publish, wave 0 reduces + stores
  if (wid != 0) {
    float* cp = &comb[wid-1][lane][0];
    cp[0] = o0[0]; cp[1] = o0[1]; cp[2] = o0[2]; cp[3] = o0[3];
    cp[4] = o1[0]; cp[5] = o1[1]; cp[6] = o1[2]; cp[7] = o1[3];
    cp[8] = l0;    cp[9] = l1;
  }
  __syncthreads();
  if (wid == 0) {
    #pragma unroll
    for (int wv = 0; wv < 7; ++wv) {
      const float* cp = &comb[wv][lane][0];
      o0[0] += cp[0]; o0[1] += cp[1]; o0[2] += cp[2]; o0[3] += cp[3];
      o1[0] += cp[4]; o1[1] += cp[5]; o1[2] += cp[6]; o1[3] += cp[7];
      l0 += cp[8];    l1 += cp[9];
    }
    // total l per q (lanes l^16, l^32 hold the same q)
    l0 += __shfl_xor(l0, 16); l0 += __shfl_xor(l0, 32);
    l1 += __shfl_xor(l1, 16); l1 += __shfl_xor(l1, 32);
    float inv0 = 1.0f / l0, inv1 = 1.0f / l1;

    int b = bh >> 2, h = bh & 3;
    float* ob = out + ((size_t)(b*64 + h*16 + g4)) * NTOK;
    #pragma unroll
    for (int r = 0; r < 4; ++r) {
      ob[(size_t)r*NTOK + qbase      + lr] = o0[r] * inv0;
      ob[(size_t)r*NTOK + qbase + 16 + lr] = o1[r] * inv1;
    }
  }
}

extern "C" void kernel_launch(void* const* d_in, const int* in_sizes, int n_in,
                              void* d_out, int out_size, void* d_ws, size_t ws_size,
                              hipStream_t stream) {
  const float* x    = (const float*)d_in[0];   // (2,64,64,64)
  const float* w    = (const float*)d_in[1];   // (192,64)
  const float* bias = (const float*)d_in[2];   // (192,)
  float* out  = (float*)d_out;                 // (2,64,64,64)
  ushort* wsu = (ushort*)d_ws;                 // 3 MB used (+~2KB over-read pad)

  qkv_proj <<<512,  192, 0, stream>>>(x, w, bias, wsu);
  attn_mfma<<<1024, 512, 0, stream>>>(wsu, out);
}

// Round 16
// 41.565 us; speedup vs baseline: 1.1949x; 1.0048x over previous
//
#include <hip/hip_runtime.h>
#include <hip/hip_bf16.h>

// SpatialAttention2D MFMA v15: B=2, C=64, N=4096, 4 heads x d=16, fp32 io.
// vs v12 (best, 41.35): ONE change — attn prefetch depth 2 -> 3 bodies
// (6 named fragment sets: compute A,B while P1 in flight and P2 issuing;
// effective prefetch distance ~4-5 pair-iters to cover contended-L2 latency).
// qkv_proj, grid, setprio, epilogue all byte-identical to v12.

#define NTOK 4096
#define HD   16
#define BH   8
#define QUART 1024             // keys per wave (key-quarter)
#define PITERS (QUART/32)      // 32 pair-iters (2 chunks of 16 keys each)

typedef __attribute__((ext_vector_type(4))) short short4v;
typedef __attribute__((ext_vector_type(4))) float float4v;
typedef __attribute__((ext_vector_type(4))) ushort ushort4v;
typedef __attribute__((ext_vector_type(2))) unsigned uint2v;

__device__ __forceinline__ ushort f2bf(float f) {
  unsigned u = __builtin_bit_cast(unsigned, f);
  u += 0x7fffu + ((u >> 16) & 1u);          // round-to-nearest-even
  return (ushort)(u >> 16);
}

__device__ __forceinline__ float fast_exp2(float x) {
#if __has_builtin(__builtin_amdgcn_exp2f)
  return __builtin_amdgcn_exp2f(x);
#else
  return exp2f(x);
#endif
}

// packed f32x4 -> bf16x4 (RNE) via v_cvt_pk_bf16_f32 (v6b-verified form)
__device__ __forceinline__ short4v pack4_bf16(float a, float b, float c, float d) {
  __hip_bfloat162 lo = __float22bfloat162_rn(make_float2(a, b));
  __hip_bfloat162 hi = __float22bfloat162_rn(make_float2(c, d));
  unsigned ulo, uhi;
  __builtin_memcpy(&ulo, &lo, 4);
  __builtin_memcpy(&uhi, &hi, 4);
  uint2v u = { ulo, uhi };
  return __builtin_bit_cast(short4v, u);
}

// ws layout in ushort elements (3 MB total)
// Qt: [bh][d][n] (transposed), Kb: [bh][n][d], Vf: [bh] fragment-ordered:
//   element (d, key) at bh*65536 + (key>>4)*256 + ((key&15)>>2)*64 + d*4 + (key&3)
#define QB_OFF 0
#define KB_OFF ((size_t)BH*NTOK*HD)
#define VT_OFF (2*(size_t)BH*NTOK*HD)

// ---------------------------------------------------------------------------
// Kernel 1: QKV projection (byte-identical to r12's proven kernel).
// ---------------------------------------------------------------------------
__global__ __launch_bounds__(192) void qkv_proj(
    const float* __restrict__ x, const float* __restrict__ w,
    const float* __restrict__ bias, ushort* __restrict__ wsu) {
  const int TOK = 8, TILES = 2;
  int blk = blockIdx.x;            // 512
  int b   = blk >> 8;
  int n00 = (blk & 255) * (TOK*TILES);
  int o   = threadIdx.x;           // 0..191

  float wr[64];
  const float4* w4 = reinterpret_cast<const float4*>(w + o*64);
  #pragma unroll
  for (int i = 0; i < 16; ++i) {
    float4 tt = w4[i];
    wr[4*i+0]=tt.x; wr[4*i+1]=tt.y; wr[4*i+2]=tt.z; wr[4*i+3]=tt.w;
  }
  float bb = bias[o];

  int part = o >> 6;               // 0=q,1=k,2=v
  int oo   = o & 63;
  int h    = oo >> 4;
  int dd   = oo & 15;
  int bh   = b*4 + h;
  const float QSCALE = 0.25f * 1.44269504f;

  ushort* Qt = wsu + QB_OFF;
  ushort* Kb = wsu + KB_OFF;
  ushort* Vf = wsu + VT_OFF;

  __shared__ float4 xs4[64][2];
  const float4* x4 = reinterpret_cast<const float4*>(x);

  #pragma unroll 1
  for (int tile = 0; tile < TILES; ++tile) {
    int n0 = n00 + tile*TOK;
    for (int idx = threadIdx.x; idx < 128; idx += 192) {
      int c = idx >> 1, t4 = idx & 1;
      xs4[c][t4] = x4[((size_t)b*64 + c)*(NTOK/4) + (n0 >> 2) + t4];
    }
    __syncthreads();

    #pragma unroll
    for (int t4 = 0; t4 < 2; ++t4) {
      float a[4] = {bb, bb, bb, bb};
      #pragma unroll
      for (int c = 0; c < 64; ++c) {
        float4 xv = xs4[c][t4];
        float wv = wr[c];
        a[0] = fmaf(xv.x, wv, a[0]);
        a[1] = fmaf(xv.y, wv, a[1]);
        a[2] = fmaf(xv.z, wv, a[2]);
        a[3] = fmaf(xv.w, wv, a[3]);
      }
      if (part == 0) {
        ushort4v vv = { f2bf(a[0]*QSCALE), f2bf(a[1]*QSCALE),
                        f2bf(a[2]*QSCALE), f2bf(a[3]*QSCALE) };
        *(ushort4v*)(Qt + ((size_t)bh*HD + dd)*NTOK + n0 + t4*4) = vv;
      } else if (part == 1) {
        #pragma unroll
        for (int j = 0; j < 4; ++j)
          Kb[((size_t)bh*NTOK + n0 + t4*4 + j)*HD + dd] = f2bf(a[j]);
      } else {
        int m = n0 + t4*4;
        size_t idx = (size_t)bh*NTOK*HD + (m >> 4)*256 + ((m & 15) >> 2)*64 + dd*4;
        ushort4v vv = { f2bf(a[0]), f2bf(a[1]), f2bf(a[2]), f2bf(a[3]) };
        *(ushort4v*)(Vf + idx) = vv;
      }
    }
    __syncthreads();
  }
}

// ---------------------------------------------------------------------------
// Kernel 2: register-direct MFMA flash attention (r12 structure), depth-3
// pipeline: compute {A,B} while {P1} in flight and {P2} issuing.
// Grid = 8 bh x 128 qblk(32q) = 1024 blocks x 256 threads (4 waves).
// Wave = key-quarter; all 4 waves cover the SAME 32 q. All frag loads are
// coalesced 512B/wave. Epilogue combines quarters via small LDS.
// ---------------------------------------------------------------------------
__global__ __launch_bounds__(256, 4) void attn_mfma(
    const ushort* __restrict__ wsu, float* __restrict__ out) {
  const ushort* Qt = wsu + QB_OFF;
  const ushort* Kb = wsu + KB_OFF;
  const ushort* Vt = wsu + VT_OFF;

  int bh    = blockIdx.x >> 7;
  int qblk  = blockIdx.x & 127;
  int tid   = threadIdx.x;
  int quart = tid >> 6;            // 0..3: key-quarter
  int lane  = tid & 63;
  int lr    = lane & 15;
  int g4    = (lane >> 4) << 2;
  int qbase = qblk*32;

  __shared__ float comb[3][64][11];   // 8.4 KB epilogue combine

  const ushort* Qh = Qt + (size_t)bh*HD*NTOK;                       // [d][n]
  const ushort* Kh = Kb + ((size_t)bh*NTOK + (size_t)quart*QUART)*HD;
  const ushort* Vh = Vt + (size_t)bh*NTOK*HD + (size_t)quart*QUART*HD;

  // Q fragments (B operand): lane l holds Q[q][d=g4..g4+3], q-groups 0/1
  short4v qf0, qf1;
  #pragma unroll
  for (int j = 0; j < 4; ++j) {
    qf0[j] = (short)Qh[(size_t)(g4+j)*NTOK + qbase      + lr];
    qf1[j] = (short)Qh[(size_t)(g4+j)*NTOK + qbase + 16 + lr];
  }

  // per-lane fragment pointers (ushort units); pair-iter i reads i*512 (+256)
  const ushort* kp = Kh + lr*HD + (lane >> 4)*4;
  const ushort* vp = Vh + lane*4;

  float4v a0e = {0.f,0.f,0.f,0.f}, a0o = {0.f,0.f,0.f,0.f};
  float4v a1e = {0.f,0.f,0.f,0.f}, a1o = {0.f,0.f,0.f,0.f};
  float l0 = 0.f, l1 = 0.f;

#define ITER(ke, ko, ve, vo)                                                \
  do {                                                                      \
    float4v zero = {0.f,0.f,0.f,0.f};                                       \
    __builtin_amdgcn_s_setprio(1);                                          \
    float4v s0e = __builtin_amdgcn_mfma_f32_16x16x16bf16_1k(ke, qf0, zero, 0,0,0); \
    float4v s0o = __builtin_amdgcn_mfma_f32_16x16x16bf16_1k(ko, qf0, zero, 0,0,0); \
    float4v s1e = __builtin_amdgcn_mfma_f32_16x16x16bf16_1k(ke, qf1, zero, 0,0,0); \
    float4v s1o = __builtin_amdgcn_mfma_f32_16x16x16bf16_1k(ko, qf1, zero, 0,0,0); \
    float p0e0 = fast_exp2(s0e[0]), p0e1 = fast_exp2(s0e[1]);               \
    float p0e2 = fast_exp2(s0e[2]), p0e3 = fast_exp2(s0e[3]);               \
    float p0o0 = fast_exp2(s0o[0]), p0o1 = fast_exp2(s0o[1]);               \
    float p0o2 = fast_exp2(s0o[2]), p0o3 = fast_exp2(s0o[3]);               \
    float p1e0 = fast_exp2(s1e[0]), p1e1 = fast_exp2(s1e[1]);               \
    float p1e2 = fast_exp2(s1e[2]), p1e3 = fast_exp2(s1e[3]);               \
    float p1o0 = fast_exp2(s1o[0]), p1o1 = fast_exp2(s1o[1]);               \
    float p1o2 = fast_exp2(s1o[2]), p1o3 = fast_exp2(s1o[3]);               \
    l0 += (p0e0 + p0e1) + (p0e2 + p0e3) + (p0o0 + p0o1) + (p0o2 + p0o3);    \
    l1 += (p1e0 + p1e1) + (p1e2 + p1e3) + (p1o0 + p1o1) + (p1o2 + p1o3);    \
    short4v pb0e = pack4_bf16(p0e0, p0e1, p0e2, p0e3);                      \
    short4v pb0o = pack4_bf16(p0o0, p0o1, p0o2, p0o3);                      \
    short4v pb1e = pack4_bf16(p1e0, p1e1, p1e2, p1e3);                      \
    short4v pb1o = pack4_bf16(p1o0, p1o1, p1o2, p1o3);                      \
    a0e = __builtin_amdgcn_mfma_f32_16x16x16bf16_1k(ve, pb0e, a0e, 0,0,0);  \
    a0o = __builtin_amdgcn_mfma_f32_16x16x16bf16_1k(vo, pb0o, a0o, 0,0,0);  \
    a1e = __builtin_amdgcn_mfma_f32_16x16x16bf16_1k(ve, pb1e, a1e, 0,0,0);  \
    a1o = __builtin_amdgcn_mfma_f32_16x16x16bf16_1k(vo, pb1o, a1o, 0,0,0);  \
    __builtin_amdgcn_s_setprio(0);                                          \
  } while (0)

#define LOADSET(dst_ke, dst_ko, dst_ve, dst_vo, off)                        \
    dst_ke = *(const short4v*)(kp + (off));                                 \
    dst_ko = *(const short4v*)(kp + (off) + 256);                           \
    dst_ve = *(const short4v*)(vp + (off));                                 \
    dst_vo = *(const short4v*)(vp + (off) + 256);

  // prologue: sets for pair-iters 0,1 (A,B) and 2,3 (P1a,P1b)
  short4v kAe, kAo, vAe, vAo,  kBe, kBo, vBe, vBo;
  short4v k1ae, k1ao, v1ae, v1ao,  k1be, k1bo, v1be, v1bo;
  LOADSET(kAe, kAo, vAe, vAo, 0)
  LOADSET(kBe, kBo, vBe, vBo, 512)
  LOADSET(k1ae, k1ao, v1ae, v1ao, 1024)
  LOADSET(k1be, k1bo, v1be, v1bo, 1536)

  #pragma unroll 4
  for (int it2 = 0; it2 < PITERS/2; ++it2) {
    // issue loads for pair-iters 2*it2+4 / 2*it2+5 (P2); benign ws over-read
    int oA = (2*it2 + 4) * 512;
    int oB = (2*it2 + 5) * 512;
    short4v k2ae, k2ao, v2ae, v2ao,  k2be, k2bo, v2be, v2bo;
    LOADSET(k2ae, k2ao, v2ae, v2ao, oA)
    LOADSET(k2be, k2bo, v2be, v2bo, oB)

    ITER(kAe, kAo, vAe, vAo);
    ITER(kBe, kBo, vBe, vBo);

    // rotate: A,B <- P1; P1 <- P2 (renamed away under unroll)
    kAe = k1ae; kAo = k1ao; vAe = v1ae; vAo = v1ao;
    kBe = k1be; kBo = k1bo; vBe = v1be; vBo = v1bo;
    k1ae = k2ae; k1ao = k2ao; v1ae = v2ae; v1ao = v2ao;
    k1be = k2be; k1bo = k2bo; v1be = v2be; v1bo = v2bo;
  }
#undef ITER
#undef LOADSET

  // per-wave partial outputs (key-quarter partials)
  float o0[4], o1[4];
  #pragma unroll
  for (int r = 0; r < 4; ++r) {
    o0[r] = a0e[r] + a0o[r];
    o1[r] = a1e[r] + a1o[r];
  }

  // combine the 4 quarters: waves 1..3 publish, wave 0 reduces + stores
  if (quart != 0) {
    float* cp = &comb[quart-1][lane][0];
    cp[0] = o0[0]; cp[1] = o0[1]; cp[2] = o0[2]; cp[3] = o0[3];
    cp[4] = o1[0]; cp[5] = o1[1]; cp[6] = o1[2]; cp[7] = o1[3];
    cp[8] = l0;    cp[9] = l1;
  }
  __syncthreads();
  if (quart == 0) {
    #pragma unroll
    for (int wv = 0; wv < 3; ++wv) {
      const float* cp = &comb[wv][lane][0];
      o0[0] += cp[0]; o0[1] += cp[1]; o0[2] += cp[2]; o0[3] += cp[3];
      o1[0] += cp[4]; o1[1] += cp[5]; o1[2] += cp[6]; o1[3] += cp[7];
      l0 += cp[8];    l1 += cp[9];
    }
    // total l per q (lanes l^16, l^32 hold the same q)
    l0 += __shfl_xor(l0, 16); l0 += __shfl_xor(l0, 32);
    l1 += __shfl_xor(l1, 16); l1 += __shfl_xor(l1, 32);
    float inv0 = 1.0f / l0, inv1 = 1.0f / l1;

    int b = bh >> 2, h = bh & 3;
    float* ob = out + ((size_t)(b*64 + h*16 + g4)) * NTOK;
    #pragma unroll
    for (int r = 0; r < 4; ++r) {
      ob[(size_t)r*NTOK + qbase      + lr] = o0[r] * inv0;
      ob[(size_t)r*NTOK + qbase + 16 + lr] = o1[r] * inv1;
    }
  }
}

extern "C" void kernel_launch(void* const* d_in, const int* in_sizes, int n_in,
                              void* d_out, int out_size, void* d_ws, size_t ws_size,
                              hipStream_t stream) {
  const float* x    = (const float*)d_in[0];   // (2,64,64,64)
  const float* w    = (const float*)d_in[1];   // (192,64)
  const float* bias = (const float*)d_in[2];   // (192,)
  float* out  = (float*)d_out;                 // (2,64,64,64)
  ushort* wsu = (ushort*)d_ws;                 // 3 MB used (+~6KB over-read pad)

  qkv_proj <<<512,  192, 0, stream>>>(x, w, bias, wsu);
  attn_mfma<<<1024, 256, 0, stream>>>(wsu, out);
}

// Round 17
// 41.307 us; speedup vs baseline: 1.2023x; 1.0062x over previous
//
#include <hip/hip_runtime.h>
#include <hip/hip_bf16.h>

// SpatialAttention2D MFMA v16: B=2, C=64, N=4096, 4 heads x d=16, fp32 io.
// vs v11 (best, 41.35): ONE mechanism — VMEM instruction count per ITER cut
// 8 -> 2 by storing K AND V pair-interleaved fragment-ordered in global:
// lane l's even+odd chunk fragments for pair-iter i are contiguous 16B at
// unit i*512 + lane*8 (ushorts). attn loads one dwordx4 for K and one for V
// per ITER and splits in-register (shufflevector). Targets the per-CU
// vector-memory address/miss throughput wall (only model consistent with
// occupancy/prefetch/BW all-neutral results). qkv: same store counts,
// remapped indices. attn otherwise byte-identical to v11.

#define NTOK 4096
#define HD   16
#define BH   8
#define QUART 1024             // keys per wave (key-quarter)
#define PITERS (QUART/32)      // 32 pair-iters (2 chunks of 16 keys each)

typedef __attribute__((ext_vector_type(4))) short short4v;
typedef __attribute__((ext_vector_type(8))) short short8v;
typedef __attribute__((ext_vector_type(4))) float float4v;
typedef __attribute__((ext_vector_type(4))) ushort ushort4v;
typedef __attribute__((ext_vector_type(2))) unsigned uint2v;

__device__ __forceinline__ ushort f2bf(float f) {
  unsigned u = __builtin_bit_cast(unsigned, f);
  u += 0x7fffu + ((u >> 16) & 1u);          // round-to-nearest-even
  return (ushort)(u >> 16);
}

__device__ __forceinline__ float fast_exp2(float x) {
#if __has_builtin(__builtin_amdgcn_exp2f)
  return __builtin_amdgcn_exp2f(x);
#else
  return exp2f(x);
#endif
}

// packed f32x4 -> bf16x4 (RNE) via v_cvt_pk_bf16_f32 (v6b-verified form)
__device__ __forceinline__ short4v pack4_bf16(float a, float b, float c, float d) {
  __hip_bfloat162 lo = __float22bfloat162_rn(make_float2(a, b));
  __hip_bfloat162 hi = __float22bfloat162_rn(make_float2(c, d));
  unsigned ulo, uhi;
  __builtin_memcpy(&ulo, &lo, 4);
  __builtin_memcpy(&uhi, &hi, 4);
  uint2v u = { ulo, uhi };
  return __builtin_bit_cast(short4v, u);
}

// ws layout in ushort elements (3 MB total)
// Qt: [bh][d][n] (transposed).
// Kp (pair-frag): element (key n, d) at unit (n>>5)*512 +
//     ((d>>2)*16 + (n&15))*8 + ((n>>4)&1)*4 + (d&3)
// Vp (pair-frag): element (d, key n) at unit (n>>5)*512 +
//     (((n&15)>>2)*16 + d)*8 + ((n>>4)&1)*4 + (n&3)
// Both: lane l, pair-iter i reads 16B at i*512 + l*8 = [even frag | odd frag].
#define QB_OFF 0
#define KB_OFF ((size_t)BH*NTOK*HD)
#define VT_OFF (2*(size_t)BH*NTOK*HD)

// ---------------------------------------------------------------------------
// Kernel 1: QKV projection (r12 structure; K/V store indices remapped to the
// pair-frag layouts — same store instruction counts). Q scaled by
// 0.25*log2(e), stored [d][n].
// ---------------------------------------------------------------------------
__global__ __launch_bounds__(192) void qkv_proj(
    const float* __restrict__ x, const float* __restrict__ w,
    const float* __restrict__ bias, ushort* __restrict__ wsu) {
  const int TOK = 8, TILES = 2;
  int blk = blockIdx.x;            // 512
  int b   = blk >> 8;
  int n00 = (blk & 255) * (TOK*TILES);
  int o   = threadIdx.x;           // 0..191

  float wr[64];
  const float4* w4 = reinterpret_cast<const float4*>(w + o*64);
  #pragma unroll
  for (int i = 0; i < 16; ++i) {
    float4 tt = w4[i];
    wr[4*i+0]=tt.x; wr[4*i+1]=tt.y; wr[4*i+2]=tt.z; wr[4*i+3]=tt.w;
  }
  float bb = bias[o];

  int part = o >> 6;               // 0=q,1=k,2=v
  int oo   = o & 63;
  int h    = oo >> 4;
  int dd   = oo & 15;
  int bh   = b*4 + h;
  const float QSCALE = 0.25f * 1.44269504f;

  ushort* Qt = wsu + QB_OFF;
  ushort* Kp = wsu + KB_OFF;
  ushort* Vp = wsu + VT_OFF;

  __shared__ float4 xs4[64][2];
  const float4* x4 = reinterpret_cast<const float4*>(x);

  #pragma unroll 1
  for (int tile = 0; tile < TILES; ++tile) {
    int n0 = n00 + tile*TOK;
    for (int idx = threadIdx.x; idx < 128; idx += 192) {
      int c = idx >> 1, t4 = idx & 1;
      xs4[c][t4] = x4[((size_t)b*64 + c)*(NTOK/4) + (n0 >> 2) + t4];
    }
    __syncthreads();

    #pragma unroll
    for (int t4 = 0; t4 < 2; ++t4) {
      float a[4] = {bb, bb, bb, bb};
      #pragma unroll
      for (int c = 0; c < 64; ++c) {
        float4 xv = xs4[c][t4];
        float wv = wr[c];
        a[0] = fmaf(xv.x, wv, a[0]);
        a[1] = fmaf(xv.y, wv, a[1]);
        a[2] = fmaf(xv.z, wv, a[2]);
        a[3] = fmaf(xv.w, wv, a[3]);
      }
      if (part == 0) {
        ushort4v vv = { f2bf(a[0]*QSCALE), f2bf(a[1]*QSCALE),
                        f2bf(a[2]*QSCALE), f2bf(a[3]*QSCALE) };
        *(ushort4v*)(Qt + ((size_t)bh*HD + dd)*NTOK + n0 + t4*4) = vv;
      } else if (part == 1) {
        // pair-frag K: 4 scalar stores (j varies n&15 -> stride 8 units)
        #pragma unroll
        for (int j = 0; j < 4; ++j) {
          int n = n0 + t4*4 + j;
          size_t idx = (size_t)bh*NTOK*HD + (n >> 5)*512
                     + ((dd >> 2)*16 + (n & 15))*8 + ((n >> 4) & 1)*4 + (dd & 3);
          Kp[idx] = f2bf(a[j]);
        }
      } else {
        // pair-frag V: tokens m..m+3 (m%4==0) are consecutive units
        int m = n0 + t4*4;
        size_t idx = (size_t)bh*NTOK*HD + (m >> 5)*512
                   + (((m & 15) >> 2)*16 + dd)*8 + ((m >> 4) & 1)*4;
        ushort4v vv = { f2bf(a[0]), f2bf(a[1]), f2bf(a[2]), f2bf(a[3]) };
        *(ushort4v*)(Vp + idx) = vv;
      }
    }
    __syncthreads();
  }
}

// ---------------------------------------------------------------------------
// Kernel 2: register-direct MFMA flash attention (v11 structure), depth-2
// pipeline, 2 VMEM instructions per ITER (16B K-pair + 16B V-pair).
// Grid = 8 bh x 128 qblk(32q) = 1024 blocks x 256 threads (4 waves).
// Wave = key-quarter; all 4 waves cover the SAME 32 q.
// ---------------------------------------------------------------------------
__global__ __launch_bounds__(256, 4) void attn_mfma(
    const ushort* __restrict__ wsu, float* __restrict__ out) {
  const ushort* Qt = wsu + QB_OFF;
  const ushort* Kp = wsu + KB_OFF;
  const ushort* Vp = wsu + VT_OFF;

  int bh    = blockIdx.x >> 7;
  int qblk  = blockIdx.x & 127;
  int tid   = threadIdx.x;
  int quart = tid >> 6;            // 0..3: key-quarter
  int lane  = tid & 63;
  int lr    = lane & 15;
  int g4    = (lane >> 4) << 2;
  int qbase = qblk*32;

  __shared__ float comb[3][64][11];   // 8.4 KB epilogue combine

  const ushort* Qh = Qt + (size_t)bh*HD*NTOK;                       // [d][n]
  const ushort* KhF = Kp + (size_t)bh*NTOK*HD + (size_t)quart*QUART*HD;
  const ushort* VhF = Vp + (size_t)bh*NTOK*HD + (size_t)quart*QUART*HD;

  // Q fragments (B operand): lane l holds Q[q][d=g4..g4+3], q-groups 0/1
  short4v qf0, qf1;
  #pragma unroll
  for (int j = 0; j < 4; ++j) {
    qf0[j] = (short)Qh[(size_t)(g4+j)*NTOK + qbase      + lr];
    qf1[j] = (short)Qh[(size_t)(g4+j)*NTOK + qbase + 16 + lr];
  }

  // per-lane 16B pair-fragment pointers; pair-iter i reads at i*512 (ushorts)
  const ushort* kp16 = KhF + lane*8;
  const ushort* vp16 = VhF + lane*8;

  float4v a0e = {0.f,0.f,0.f,0.f}, a0o = {0.f,0.f,0.f,0.f};
  float4v a1e = {0.f,0.f,0.f,0.f}, a1o = {0.f,0.f,0.f,0.f};
  float l0 = 0.f, l1 = 0.f;

#define ITER(kpr, vpr)                                                      \
  do {                                                                      \
    short4v ke = __builtin_shufflevector(kpr, kpr, 0,1,2,3);                \
    short4v ko = __builtin_shufflevector(kpr, kpr, 4,5,6,7);                \
    short4v ve = __builtin_shufflevector(vpr, vpr, 0,1,2,3);                \
    short4v vo = __builtin_shufflevector(vpr, vpr, 4,5,6,7);                \
    float4v zero = {0.f,0.f,0.f,0.f};                                       \
    __builtin_amdgcn_s_setprio(1);                                          \
    float4v s0e = __builtin_amdgcn_mfma_f32_16x16x16bf16_1k(ke, qf0, zero, 0,0,0); \
    float4v s0o = __builtin_amdgcn_mfma_f32_16x16x16bf16_1k(ko, qf0, zero, 0,0,0); \
    float4v s1e = __builtin_amdgcn_mfma_f32_16x16x16bf16_1k(ke, qf1, zero, 0,0,0); \
    float4v s1o = __builtin_amdgcn_mfma_f32_16x16x16bf16_1k(ko, qf1, zero, 0,0,0); \
    float p0e0 = fast_exp2(s0e[0]), p0e1 = fast_exp2(s0e[1]);               \
    float p0e2 = fast_exp2(s0e[2]), p0e3 = fast_exp2(s0e[3]);               \
    float p0o0 = fast_exp2(s0o[0]), p0o1 = fast_exp2(s0o[1]);               \
    float p0o2 = fast_exp2(s0o[2]), p0o3 = fast_exp2(s0o[3]);               \
    float p1e0 = fast_exp2(s1e[0]), p1e1 = fast_exp2(s1e[1]);               \
    float p1e2 = fast_exp2(s1e[2]), p1e3 = fast_exp2(s1e[3]);               \
    float p1o0 = fast_exp2(s1o[0]), p1o1 = fast_exp2(s1o[1]);               \
    float p1o2 = fast_exp2(s1o[2]), p1o3 = fast_exp2(s1o[3]);               \
    l0 += (p0e0 + p0e1) + (p0e2 + p0e3) + (p0o0 + p0o1) + (p0o2 + p0o3);    \
    l1 += (p1e0 + p1e1) + (p1e2 + p1e3) + (p1o0 + p1o1) + (p1o2 + p1o3);    \
    short4v pb0e = pack4_bf16(p0e0, p0e1, p0e2, p0e3);                      \
    short4v pb0o = pack4_bf16(p0o0, p0o1, p0o2, p0o3);                      \
    short4v pb1e = pack4_bf16(p1e0, p1e1, p1e2, p1e3);                      \
    short4v pb1o = pack4_bf16(p1o0, p1o1, p1o2, p1o3);                      \
    a0e = __builtin_amdgcn_mfma_f32_16x16x16bf16_1k(ve, pb0e, a0e, 0,0,0);  \
    a0o = __builtin_amdgcn_mfma_f32_16x16x16bf16_1k(vo, pb0o, a0o, 0,0,0);  \
    a1e = __builtin_amdgcn_mfma_f32_16x16x16bf16_1k(ve, pb1e, a1e, 0,0,0);  \
    a1o = __builtin_amdgcn_mfma_f32_16x16x16bf16_1k(vo, pb1o, a1o, 0,0,0);  \
    __builtin_amdgcn_s_setprio(0);                                          \
  } while (0)

  // prologue: pair-fragments for iters 0 (A) and 1 (B)
  short8v kA = *(const short8v*)(kp16);
  short8v vA = *(const short8v*)(vp16);
  short8v kB = *(const short8v*)(kp16 + 512);
  short8v vB = *(const short8v*)(vp16 + 512);

  #pragma unroll 4
  for (int it2 = 0; it2 < PITERS/2; ++it2) {
    // prefetch iters 2*it2+2 (A') and 2*it2+3 (B'); benign ws over-read at tail
    int oA = (2*it2 + 2) * 512;
    int oB = (2*it2 + 3) * 512;
    short8v nkA = *(const short8v*)(kp16 + oA);
    short8v nvA = *(const short8v*)(vp16 + oA);
    short8v nkB = *(const short8v*)(kp16 + oB);
    short8v nvB = *(const short8v*)(vp16 + oB);

    ITER(kA, vA);
    ITER(kB, vB);

    kA = nkA; vA = nvA; kB = nkB; vB = nvB;
  }
#undef ITER

  // per-wave partial outputs (key-quarter partials)
  float o0[4], o1[4];
  #pragma unroll
  for (int r = 0; r < 4; ++r) {
    o0[r] = a0e[r] + a0o[r];
    o1[r] = a1e[r] + a1o[r];
  }

  // combine the 4 quarters: waves 1..3 publish, wave 0 reduces + stores
  if (quart != 0) {
    float* cp = &comb[quart-1][lane][0];
    cp[0] = o0[0]; cp[1] = o0[1]; cp[2] = o0[2]; cp[3] = o0[3];
    cp[4] = o1[0]; cp[5] = o1[1]; cp[6] = o1[2]; cp[7] = o1[3];
    cp[8] = l0;    cp[9] = l1;
  }
  __syncthreads();
  if (quart == 0) {
    #pragma unroll
    for (int wv = 0; wv < 3; ++wv) {
      const float* cp = &comb[wv][lane][0];
      o0[0] += cp[0]; o0[1] += cp[1]; o0[2] += cp[2]; o0[3] += cp[3];
      o1[0] += cp[4]; o1[1] += cp[5]; o1[2] += cp[6]; o1[3] += cp[7];
      l0 += cp[8];    l1 += cp[9];
    }
    // total l per q (lanes l^16, l^32 hold the same q)
    l0 += __shfl_xor(l0, 16); l0 += __shfl_xor(l0, 32);
    l1 += __shfl_xor(l1, 16); l1 += __shfl_xor(l1, 32);
    float inv0 = 1.0f / l0, inv1 = 1.0f / l1;

    int b = bh >> 2, h = bh & 3;
    float* ob = out + ((size_t)(b*64 + h*16 + g4)) * NTOK;
    #pragma unroll
    for (int r = 0; r < 4; ++r) {
      ob[(size_t)r*NTOK + qbase      + lr] = o0[r] * inv0;
      ob[(size_t)r*NTOK + qbase + 16 + lr] = o1[r] * inv1;
    }
  }
}

extern "C" void kernel_launch(void* const* d_in, const int* in_sizes, int n_in,
                              void* d_out, int out_size, void* d_ws, size_t ws_size,
                              hipStream_t stream) {
  const float* x    = (const float*)d_in[0];   // (2,64,64,64)
  const float* w    = (const float*)d_in[1];   // (192,64)
  const float* bias = (const float*)d_in[2];   // (192,)
  float* out  = (float*)d_out;                 // (2,64,64,64)
  ushort* wsu = (ushort*)d_ws;                 // 3 MB used (+~2KB over-read pad)

  qkv_proj <<<512,  192, 0, stream>>>(x, w, bias, wsu);
  attn_mfma<<<1024, 256, 0, stream>>>(wsu, out);
}

// Round 18
// 37.400 us; speedup vs baseline: 1.3279x; 1.1045x over previous
//
#include <hip/hip_runtime.h>
#include <hip/hip_bf16.h>

// SpatialAttention2D MFMA v17: B=2, C=64, N=4096, 4 heads x d=16, fp32 io.
// vs v16 (equal-best, 41.31): attn BYTE-IDENTICAL. qkv redesigned for
// occupancy: thread = (token, 4-channel group); block = 64 tokens x one
// (part,head) 16-channel slice (w slice 4KB in LDS, wave-uniform broadcast
// reads); grid 1536 blocks, ~40 VGPR, 24 waves/CU (vs 6 before). x loads
// lane-coalesced; same-token blocks land on the same XCD (tg = blk&127,
// 128 % 8 == 0) so the 12x x re-read hits per-XCD L2. Q [d][n] scalar
// stores; K single 8B pair-frag store; V 4 scalar pair-frag stores.

#define NTOK 4096
#define HD   16
#define BH   8
#define QUART 1024             // keys per wave (key-quarter)
#define PITERS (QUART/32)      // 32 pair-iters (2 chunks of 16 keys each)

typedef __attribute__((ext_vector_type(4))) short short4v;
typedef __attribute__((ext_vector_type(8))) short short8v;
typedef __attribute__((ext_vector_type(4))) float float4v;
typedef __attribute__((ext_vector_type(4))) ushort ushort4v;
typedef __attribute__((ext_vector_type(2))) unsigned uint2v;

__device__ __forceinline__ ushort f2bf(float f) {
  unsigned u = __builtin_bit_cast(unsigned, f);
  u += 0x7fffu + ((u >> 16) & 1u);          // round-to-nearest-even
  return (ushort)(u >> 16);
}

__device__ __forceinline__ float fast_exp2(float x) {
#if __has_builtin(__builtin_amdgcn_exp2f)
  return __builtin_amdgcn_exp2f(x);
#else
  return exp2f(x);
#endif
}

// packed f32x4 -> bf16x4 (RNE) via v_cvt_pk_bf16_f32 (v6b-verified form)
__device__ __forceinline__ short4v pack4_bf16(float a, float b, float c, float d) {
  __hip_bfloat162 lo = __float22bfloat162_rn(make_float2(a, b));
  __hip_bfloat162 hi = __float22bfloat162_rn(make_float2(c, d));
  unsigned ulo, uhi;
  __builtin_memcpy(&ulo, &lo, 4);
  __builtin_memcpy(&uhi, &hi, 4);
  uint2v u = { ulo, uhi };
  return __builtin_bit_cast(short4v, u);
}

// ws layout in ushort elements (3 MB total)
// Qt: [bh][d][n] (transposed).
// Kp (pair-frag): element (key n, d) at unit (n>>5)*512 +
//     ((d>>2)*16 + (n&15))*8 + ((n>>4)&1)*4 + (d&3)
// Vp (pair-frag): element (d, key n) at unit (n>>5)*512 +
//     (((n&15)>>2)*16 + d)*8 + ((n>>4)&1)*4 + (n&3)
// Both: lane l, pair-iter i reads 16B at i*512 + l*8 = [even frag | odd frag].
#define QB_OFF 0
#define KB_OFF ((size_t)BH*NTOK*HD)
#define VT_OFF (2*(size_t)BH*NTOK*HD)

// ---------------------------------------------------------------------------
// Kernel 1: QKV projection, high-occupancy form.
// Grid = 12 gg x 128 tg = 1536 blocks x 256 threads.
//   gg -> (part = gg>>2, head = gg&3): one 16-channel slice per block.
//   thread -> token t = tg*64 + (tid&63), d-group dg = tid>>6 (4 channels).
// w slice (16 ch x 64) staged in LDS once; read as wave-uniform float4
// broadcasts. x chunked 16-at-a-time (16 VGPRs, not 64 — avoids r14's spill).
// ---------------------------------------------------------------------------
__global__ __launch_bounds__(256) void qkv_proj(
    const float* __restrict__ x, const float* __restrict__ w,
    const float* __restrict__ bias, ushort* __restrict__ wsu) {
  int tg   = blockIdx.x & 127;     // token group; same tg -> same XCD (128%8==0)
  int gg   = blockIdx.x >> 7;      // 0..11: 16-channel slice
  int part = gg >> 2;              // 0=q,1=k,2=v
  int h    = gg & 3;
  int lane = threadIdx.x & 63;
  int dg   = threadIdx.x >> 6;     // 0..3: d-subgroup
  int t    = tg*64 + lane;         // global token 0..8191
  int b    = t >> 12;
  int np   = t & 4095;
  int bh   = b*4 + h;
  const float QSCALE = 0.25f * 1.44269504f;

  __shared__ float4 wls[16][16];   // 16 channels x 64 floats = 4 KB
  __shared__ float  bls[16];

  {
    const float4* wg = reinterpret_cast<const float4*>(w + (size_t)gg*16*64);
    wls[threadIdx.x >> 4][threadIdx.x & 15] = wg[threadIdx.x];
    if (threadIdx.x < 16) bls[threadIdx.x] = bias[gg*16 + threadIdx.x];
  }
  __syncthreads();

  float acc0 = bls[dg*4+0], acc1 = bls[dg*4+1];
  float acc2 = bls[dg*4+2], acc3 = bls[dg*4+3];
  const float* xp = x + ((size_t)b*64)*NTOK + np;

  #pragma unroll
  for (int cc = 0; cc < 4; ++cc) {
    float xr[16];
    #pragma unroll
    for (int i = 0; i < 16; ++i)
      xr[i] = xp[(size_t)(cc*16 + i)*NTOK];
    #pragma unroll
    for (int i4 = 0; i4 < 4; ++i4) {
      float4 w0 = wls[dg*4+0][cc*4+i4];
      float4 w1 = wls[dg*4+1][cc*4+i4];
      float4 w2 = wls[dg*4+2][cc*4+i4];
      float4 w3 = wls[dg*4+3][cc*4+i4];
      acc0 = fmaf(xr[i4*4+0], w0.x, acc0); acc0 = fmaf(xr[i4*4+1], w0.y, acc0);
      acc0 = fmaf(xr[i4*4+2], w0.z, acc0); acc0 = fmaf(xr[i4*4+3], w0.w, acc0);
      acc1 = fmaf(xr[i4*4+0], w1.x, acc1); acc1 = fmaf(xr[i4*4+1], w1.y, acc1);
      acc1 = fmaf(xr[i4*4+2], w1.z, acc1); acc1 = fmaf(xr[i4*4+3], w1.w, acc1);
      acc2 = fmaf(xr[i4*4+0], w2.x, acc2); acc2 = fmaf(xr[i4*4+1], w2.y, acc2);
      acc2 = fmaf(xr[i4*4+2], w2.z, acc2); acc2 = fmaf(xr[i4*4+3], w2.w, acc2);
      acc3 = fmaf(xr[i4*4+0], w3.x, acc3); acc3 = fmaf(xr[i4*4+1], w3.y, acc3);
      acc3 = fmaf(xr[i4*4+2], w3.z, acc3); acc3 = fmaf(xr[i4*4+3], w3.w, acc3);
    }
  }

  int dd0 = dg*4;
  if (part == 0) {                 // Qt [d][n]: 4 scalar stores, lane-coalesced
    ushort* Qt = wsu + QB_OFF + (size_t)bh*HD*NTOK + np;
    Qt[(size_t)(dd0+0)*NTOK] = f2bf(acc0*QSCALE);
    Qt[(size_t)(dd0+1)*NTOK] = f2bf(acc1*QSCALE);
    Qt[(size_t)(dd0+2)*NTOK] = f2bf(acc2*QSCALE);
    Qt[(size_t)(dd0+3)*NTOK] = f2bf(acc3*QSCALE);
  } else if (part == 1) {          // Kp pair-frag: d&3 consecutive -> one 8B store
    size_t idx = (size_t)bh*NTOK*HD + (size_t)(np >> 5)*512
               + ((dd0 >> 2)*16 + (np & 15))*8 + ((np >> 4) & 1)*4;
    ushort4v vv = { f2bf(acc0), f2bf(acc1), f2bf(acc2), f2bf(acc3) };
    *(ushort4v*)(wsu + KB_OFF + idx) = vv;
  } else {                         // Vp pair-frag: 4 scalar stores, 8-unit stride
    size_t base = (size_t)bh*NTOK*HD + (size_t)(np >> 5)*512
                + ((np >> 4) & 1)*4 + (np & 3);
    ushort* Vp = wsu + VT_OFF + base;
    Vp[(((np & 15) >> 2)*16 + dd0+0)*8] = f2bf(acc0);
    Vp[(((np & 15) >> 2)*16 + dd0+1)*8] = f2bf(acc1);
    Vp[(((np & 15) >> 2)*16 + dd0+2)*8] = f2bf(acc2);
    Vp[(((np & 15) >> 2)*16 + dd0+3)*8] = f2bf(acc3);
  }
}

// ---------------------------------------------------------------------------
// Kernel 2: register-direct MFMA flash attention (byte-identical to v16).
// Grid = 8 bh x 128 qblk(32q) = 1024 blocks x 256 threads (4 waves).
// Wave = key-quarter; 2 VMEM instructions per ITER (16B K-pair + 16B V-pair).
// ---------------------------------------------------------------------------
__global__ __launch_bounds__(256, 4) void attn_mfma(
    const ushort* __restrict__ wsu, float* __restrict__ out) {
  const ushort* Qt = wsu + QB_OFF;
  const ushort* Kp = wsu + KB_OFF;
  const ushort* Vp = wsu + VT_OFF;

  int bh    = blockIdx.x >> 7;
  int qblk  = blockIdx.x & 127;
  int tid   = threadIdx.x;
  int quart = tid >> 6;            // 0..3: key-quarter
  int lane  = tid & 63;
  int lr    = lane & 15;
  int g4    = (lane >> 4) << 2;
  int qbase = qblk*32;

  __shared__ float comb[3][64][11];   // 8.4 KB epilogue combine

  const ushort* Qh = Qt + (size_t)bh*HD*NTOK;                       // [d][n]
  const ushort* KhF = Kp + (size_t)bh*NTOK*HD + (size_t)quart*QUART*HD;
  const ushort* VhF = Vp + (size_t)bh*NTOK*HD + (size_t)quart*QUART*HD;

  // Q fragments (B operand): lane l holds Q[q][d=g4..g4+3], q-groups 0/1
  short4v qf0, qf1;
  #pragma unroll
  for (int j = 0; j < 4; ++j) {
    qf0[j] = (short)Qh[(size_t)(g4+j)*NTOK + qbase      + lr];
    qf1[j] = (short)Qh[(size_t)(g4+j)*NTOK + qbase + 16 + lr];
  }

  // per-lane 16B pair-fragment pointers; pair-iter i reads at i*512 (ushorts)
  const ushort* kp16 = KhF + lane*8;
  const ushort* vp16 = VhF + lane*8;

  float4v a0e = {0.f,0.f,0.f,0.f}, a0o = {0.f,0.f,0.f,0.f};
  float4v a1e = {0.f,0.f,0.f,0.f}, a1o = {0.f,0.f,0.f,0.f};
  float l0 = 0.f, l1 = 0.f;

#define ITER(kpr, vpr)                                                      \
  do {                                                                      \
    short4v ke = __builtin_shufflevector(kpr, kpr, 0,1,2,3);                \
    short4v ko = __builtin_shufflevector(kpr, kpr, 4,5,6,7);                \
    short4v ve = __builtin_shufflevector(vpr, vpr, 0,1,2,3);                \
    short4v vo = __builtin_shufflevector(vpr, vpr, 4,5,6,7);                \
    float4v zero = {0.f,0.f,0.f,0.f};                                       \
    __builtin_amdgcn_s_setprio(1);                                          \
    float4v s0e = __builtin_amdgcn_mfma_f32_16x16x16bf16_1k(ke, qf0, zero, 0,0,0); \
    float4v s0o = __builtin_amdgcn_mfma_f32_16x16x16bf16_1k(ko, qf0, zero, 0,0,0); \
    float4v s1e = __builtin_amdgcn_mfma_f32_16x16x16bf16_1k(ke, qf1, zero, 0,0,0); \
    float4v s1o = __builtin_amdgcn_mfma_f32_16x16x16bf16_1k(ko, qf1, zero, 0,0,0); \
    float p0e0 = fast_exp2(s0e[0]), p0e1 = fast_exp2(s0e[1]);               \
    float p0e2 = fast_exp2(s0e[2]), p0e3 = fast_exp2(s0e[3]);               \
    float p0o0 = fast_exp2(s0o[0]), p0o1 = fast_exp2(s0o[1]);               \
    float p0o2 = fast_exp2(s0o[2]), p0o3 = fast_exp2(s0o[3]);               \
    float p1e0 = fast_exp2(s1e[0]), p1e1 = fast_exp2(s1e[1]);               \
    float p1e2 = fast_exp2(s1e[2]), p1e3 = fast_exp2(s1e[3]);               \
    float p1o0 = fast_exp2(s1o[0]), p1o1 = fast_exp2(s1o[1]);               \
    float p1o2 = fast_exp2(s1o[2]), p1o3 = fast_exp2(s1o[3]);               \
    l0 += (p0e0 + p0e1) + (p0e2 + p0e3) + (p0o0 + p0o1) + (p0o2 + p0o3);    \
    l1 += (p1e0 + p1e1) + (p1e2 + p1e3) + (p1o0 + p1o1) + (p1o2 + p1o3);    \
    short4v pb0e = pack4_bf16(p0e0, p0e1, p0e2, p0e3);                      \
    short4v pb0o = pack4_bf16(p0o0, p0o1, p0o2, p0o3);                      \
    short4v pb1e = pack4_bf16(p1e0, p1e1, p1e2, p1e3);                      \
    short4v pb1o = pack4_bf16(p1o0, p1o1, p1o2, p1o3);                      \
    a0e = __builtin_amdgcn_mfma_f32_16x16x16bf16_1k(ve, pb0e, a0e, 0,0,0);  \
    a0o = __builtin_amdgcn_mfma_f32_16x16x16bf16_1k(vo, pb0o, a0o, 0,0,0);  \
    a1e = __builtin_amdgcn_mfma_f32_16x16x16bf16_1k(ve, pb1e, a1e, 0,0,0);  \
    a1o = __builtin_amdgcn_mfma_f32_16x16x16bf16_1k(vo, pb1o, a1o, 0,0,0);  \
    __builtin_amdgcn_s_setprio(0);                                          \
  } while (0)

  // prologue: pair-fragments for iters 0 (A) and 1 (B)
  short8v kA = *(const short8v*)(kp16);
  short8v vA = *(const short8v*)(vp16);
  short8v kB = *(const short8v*)(kp16 + 512);
  short8v vB = *(const short8v*)(vp16 + 512);

  #pragma unroll 4
  for (int it2 = 0; it2 < PITERS/2; ++it2) {
    // prefetch iters 2*it2+2 (A') and 2*it2+3 (B'); benign ws over-read at tail
    int oA = (2*it2 + 2) * 512;
    int oB = (2*it2 + 3) * 512;
    short8v nkA = *(const short8v*)(kp16 + oA);
    short8v nvA = *(const short8v*)(vp16 + oA);
    short8v nkB = *(const short8v*)(kp16 + oB);
    short8v nvB = *(const short8v*)(vp16 + oB);

    ITER(kA, vA);
    ITER(kB, vB);

    kA = nkA; vA = nvA; kB = nkB; vB = nvB;
  }
#undef ITER

  // per-wave partial outputs (key-quarter partials)
  float o0[4], o1[4];
  #pragma unroll
  for (int r = 0; r < 4; ++r) {
    o0[r] = a0e[r] + a0o[r];
    o1[r] = a1e[r] + a1o[r];
  }

  // combine the 4 quarters: waves 1..3 publish, wave 0 reduces + stores
  if (quart != 0) {
    float* cp = &comb[quart-1][lane][0];
    cp[0] = o0[0]; cp[1] = o0[1]; cp[2] = o0[2]; cp[3] = o0[3];
    cp[4] = o1[0]; cp[5] = o1[1]; cp[6] = o1[2]; cp[7] = o1[3];
    cp[8] = l0;    cp[9] = l1;
  }
  __syncthreads();
  if (quart == 0) {
    #pragma unroll
    for (int wv = 0; wv < 3; ++wv) {
      const float* cp = &comb[wv][lane][0];
      o0[0] += cp[0]; o0[1] += cp[1]; o0[2] += cp[2]; o0[3] += cp[3];
      o1[0] += cp[4]; o1[1] += cp[5]; o1[2] += cp[6]; o1[3] += cp[7];
      l0 += cp[8];    l1 += cp[9];
    }
    // total l per q (lanes l^16, l^32 hold the same q)
    l0 += __shfl_xor(l0, 16); l0 += __shfl_xor(l0, 32);
    l1 += __shfl_xor(l1, 16); l1 += __shfl_xor(l1, 32);
    float inv0 = 1.0f / l0, inv1 = 1.0f / l1;

    int b = bh >> 2, h = bh & 3;
    float* ob = out + ((size_t)(b*64 + h*16 + g4)) * NTOK;
    #pragma unroll
    for (int r = 0; r < 4; ++r) {
      ob[(size_t)r*NTOK + qbase      + lr] = o0[r] * inv0;
      ob[(size_t)r*NTOK + qbase + 16 + lr] = o1[r] * inv1;
    }
  }
}

extern "C" void kernel_launch(void* const* d_in, const int* in_sizes, int n_in,
                              void* d_out, int out_size, void* d_ws, size_t ws_size,
                              hipStream_t stream) {
  const float* x    = (const float*)d_in[0];   // (2,64,64,64)
  const float* w    = (const float*)d_in[1];   // (192,64)
  const float* bias = (const float*)d_in[2];   // (192,)
  float* out  = (float*)d_out;                 // (2,64,64,64)
  ushort* wsu = (ushort*)d_ws;                 // 3 MB used (+~2KB over-read pad)

  qkv_proj <<<1536, 256, 0, stream>>>(x, w, bias, wsu);
  attn_mfma<<<1024, 256, 0, stream>>>(wsu, out);
}

// Round 19
// 35.431 us; speedup vs baseline: 1.4017x; 1.0556x over previous
//
#include <hip/hip_runtime.h>
#include <hip/hip_bf16.h>

// SpatialAttention2D MFMA v18: B=2, C=64, N=4096, 4 heads x d=16, fp32 io.
// vs v17 (best, 37.40): attn ITER trimmed for issue-port pressure:
//  (1) PV uses mfma_f32_16x16x32_bf16 (K=32 = even+odd chunk in ONE MFMA;
//      operand = [even frag | odd frag] two-half structure) -> 4 PV MFMAs
//      become 2; accumulators merge 16->8 regs.
//  (2) lsum computed by ones-MFMA (A=1.0 broadcast): removes ~14 VALU adds
//      per ITER and the epilogue cross-lane shuffles entirely.
// Correctness note: A(V) and B(P) elements at equal (lane-group, j) hold the
// same physical key's values by construction, so the contraction is correct
// under either hardware k-labeling convention. qkv byte-identical to v17.

#define NTOK 4096
#define HD   16
#define BH   8
#define QUART 1024             // keys per wave (key-quarter)
#define PITERS (QUART/32)      // 32 pair-iters (2 chunks of 16 keys each)

typedef __attribute__((ext_vector_type(4))) short short4v;
typedef __attribute__((ext_vector_type(8))) short short8v;
typedef __attribute__((ext_vector_type(4))) float float4v;
typedef __attribute__((ext_vector_type(4))) ushort ushort4v;
typedef __attribute__((ext_vector_type(2))) unsigned uint2v;

__device__ __forceinline__ ushort f2bf(float f) {
  unsigned u = __builtin_bit_cast(unsigned, f);
  u += 0x7fffu + ((u >> 16) & 1u);          // round-to-nearest-even
  return (ushort)(u >> 16);
}

__device__ __forceinline__ float fast_exp2(float x) {
#if __has_builtin(__builtin_amdgcn_exp2f)
  return __builtin_amdgcn_exp2f(x);
#else
  return exp2f(x);
#endif
}

// packed f32x4 -> bf16x4 (RNE) via v_cvt_pk_bf16_f32 (v6b-verified form)
__device__ __forceinline__ short4v pack4_bf16(float a, float b, float c, float d) {
  __hip_bfloat162 lo = __float22bfloat162_rn(make_float2(a, b));
  __hip_bfloat162 hi = __float22bfloat162_rn(make_float2(c, d));
  unsigned ulo, uhi;
  __builtin_memcpy(&ulo, &lo, 4);
  __builtin_memcpy(&uhi, &hi, 4);
  uint2v u = { ulo, uhi };
  return __builtin_bit_cast(short4v, u);
}

// ws layout in ushort elements (3 MB total)
// Qt: [bh][d][n] (transposed).
// Kp (pair-frag): element (key n, d) at unit (n>>5)*512 +
//     ((d>>2)*16 + (n&15))*8 + ((n>>4)&1)*4 + (d&3)
// Vp (pair-frag): element (d, key n) at unit (n>>5)*512 +
//     (((n&15)>>2)*16 + d)*8 + ((n>>4)&1)*4 + (n&3)
// Both: lane l, pair-iter i reads 16B at i*512 + l*8 = [even frag | odd frag].
#define QB_OFF 0
#define KB_OFF ((size_t)BH*NTOK*HD)
#define VT_OFF (2*(size_t)BH*NTOK*HD)

// ---------------------------------------------------------------------------
// Kernel 1: QKV projection, high-occupancy form (byte-identical to v17).
// ---------------------------------------------------------------------------
__global__ __launch_bounds__(256) void qkv_proj(
    const float* __restrict__ x, const float* __restrict__ w,
    const float* __restrict__ bias, ushort* __restrict__ wsu) {
  int tg   = blockIdx.x & 127;     // token group; same tg -> same XCD (128%8==0)
  int gg   = blockIdx.x >> 7;      // 0..11: 16-channel slice
  int part = gg >> 2;              // 0=q,1=k,2=v
  int h    = gg & 3;
  int lane = threadIdx.x & 63;
  int dg   = threadIdx.x >> 6;     // 0..3: d-subgroup
  int t    = tg*64 + lane;         // global token 0..8191
  int b    = t >> 12;
  int np   = t & 4095;
  int bh   = b*4 + h;
  const float QSCALE = 0.25f * 1.44269504f;

  __shared__ float4 wls[16][16];   // 16 channels x 64 floats = 4 KB
  __shared__ float  bls[16];

  {
    const float4* wg = reinterpret_cast<const float4*>(w + (size_t)gg*16*64);
    wls[threadIdx.x >> 4][threadIdx.x & 15] = wg[threadIdx.x];
    if (threadIdx.x < 16) bls[threadIdx.x] = bias[gg*16 + threadIdx.x];
  }
  __syncthreads();

  float acc0 = bls[dg*4+0], acc1 = bls[dg*4+1];
  float acc2 = bls[dg*4+2], acc3 = bls[dg*4+3];
  const float* xp = x + ((size_t)b*64)*NTOK + np;

  #pragma unroll
  for (int cc = 0; cc < 4; ++cc) {
    float xr[16];
    #pragma unroll
    for (int i = 0; i < 16; ++i)
      xr[i] = xp[(size_t)(cc*16 + i)*NTOK];
    #pragma unroll
    for (int i4 = 0; i4 < 4; ++i4) {
      float4 w0 = wls[dg*4+0][cc*4+i4];
      float4 w1 = wls[dg*4+1][cc*4+i4];
      float4 w2 = wls[dg*4+2][cc*4+i4];
      float4 w3 = wls[dg*4+3][cc*4+i4];
      acc0 = fmaf(xr[i4*4+0], w0.x, acc0); acc0 = fmaf(xr[i4*4+1], w0.y, acc0);
      acc0 = fmaf(xr[i4*4+2], w0.z, acc0); acc0 = fmaf(xr[i4*4+3], w0.w, acc0);
      acc1 = fmaf(xr[i4*4+0], w1.x, acc1); acc1 = fmaf(xr[i4*4+1], w1.y, acc1);
      acc1 = fmaf(xr[i4*4+2], w1.z, acc1); acc1 = fmaf(xr[i4*4+3], w1.w, acc1);
      acc2 = fmaf(xr[i4*4+0], w2.x, acc2); acc2 = fmaf(xr[i4*4+1], w2.y, acc2);
      acc2 = fmaf(xr[i4*4+2], w2.z, acc2); acc2 = fmaf(xr[i4*4+3], w2.w, acc2);
      acc3 = fmaf(xr[i4*4+0], w3.x, acc3); acc3 = fmaf(xr[i4*4+1], w3.y, acc3);
      acc3 = fmaf(xr[i4*4+2], w3.z, acc3); acc3 = fmaf(xr[i4*4+3], w3.w, acc3);
    }
  }

  int dd0 = dg*4;
  if (part == 0) {                 // Qt [d][n]: 4 scalar stores, lane-coalesced
    ushort* Qt = wsu + QB_OFF + (size_t)bh*HD*NTOK + np;
    Qt[(size_t)(dd0+0)*NTOK] = f2bf(acc0*QSCALE);
    Qt[(size_t)(dd0+1)*NTOK] = f2bf(acc1*QSCALE);
    Qt[(size_t)(dd0+2)*NTOK] = f2bf(acc2*QSCALE);
    Qt[(size_t)(dd0+3)*NTOK] = f2bf(acc3*QSCALE);
  } else if (part == 1) {          // Kp pair-frag: d&3 consecutive -> one 8B store
    size_t idx = (size_t)bh*NTOK*HD + (size_t)(np >> 5)*512
               + ((dd0 >> 2)*16 + (np & 15))*8 + ((np >> 4) & 1)*4;
    ushort4v vv = { f2bf(acc0), f2bf(acc1), f2bf(acc2), f2bf(acc3) };
    *(ushort4v*)(wsu + KB_OFF + idx) = vv;
  } else {                         // Vp pair-frag: 4 scalar stores, 8-unit stride
    size_t base = (size_t)bh*NTOK*HD + (size_t)(np >> 5)*512
                + ((np >> 4) & 1)*4 + (np & 3);
    ushort* Vp = wsu + VT_OFF + base;
    Vp[(((np & 15) >> 2)*16 + dd0+0)*8] = f2bf(acc0);
    Vp[(((np & 15) >> 2)*16 + dd0+1)*8] = f2bf(acc1);
    Vp[(((np & 15) >> 2)*16 + dd0+2)*8] = f2bf(acc2);
    Vp[(((np & 15) >> 2)*16 + dd0+3)*8] = f2bf(acc3);
  }
}

// ---------------------------------------------------------------------------
// Kernel 2: register-direct MFMA flash attention; K=32 PV + ones-MFMA lsum.
// Grid = 8 bh x 128 qblk(32q) = 1024 blocks x 256 threads (4 waves).
// Wave = key-quarter; 2 VMEM instructions per ITER (16B K-pair + 16B V-pair).
// ---------------------------------------------------------------------------
__global__ __launch_bounds__(256, 4) void attn_mfma(
    const ushort* __restrict__ wsu, float* __restrict__ out) {
  const ushort* Qt = wsu + QB_OFF;
  const ushort* Kp = wsu + KB_OFF;
  const ushort* Vp = wsu + VT_OFF;

  int bh    = blockIdx.x >> 7;
  int qblk  = blockIdx.x & 127;
  int tid   = threadIdx.x;
  int quart = tid >> 6;            // 0..3: key-quarter
  int lane  = tid & 63;
  int lr    = lane & 15;
  int g4    = (lane >> 4) << 2;
  int qbase = qblk*32;

  __shared__ float comb[3][64][11];   // 8.4 KB epilogue combine

  const ushort* Qh = Qt + (size_t)bh*HD*NTOK;                       // [d][n]
  const ushort* KhF = Kp + (size_t)bh*NTOK*HD + (size_t)quart*QUART*HD;
  const ushort* VhF = Vp + (size_t)bh*NTOK*HD + (size_t)quart*QUART*HD;

  // Q fragments (B operand): lane l holds Q[q][d=g4..g4+3], q-groups 0/1
  short4v qf0, qf1;
  #pragma unroll
  for (int j = 0; j < 4; ++j) {
    qf0[j] = (short)Qh[(size_t)(g4+j)*NTOK + qbase      + lr];
    qf1[j] = (short)Qh[(size_t)(g4+j)*NTOK + qbase + 16 + lr];
  }

  // per-lane 16B pair-fragment pointers; pair-iter i reads at i*512 (ushorts)
  const ushort* kp16 = KhF + lane*8;
  const ushort* vp16 = VhF + lane*8;

  const short4v one4 = {(short)0x3F80, (short)0x3F80, (short)0x3F80, (short)0x3F80};
  const short8v ones8 = {(short)0x3F80, (short)0x3F80, (short)0x3F80, (short)0x3F80,
                         (short)0x3F80, (short)0x3F80, (short)0x3F80, (short)0x3F80};
  (void)one4;

  float4v a0 = {0.f,0.f,0.f,0.f}, a1 = {0.f,0.f,0.f,0.f};
  float4v lac0 = {0.f,0.f,0.f,0.f}, lac1 = {0.f,0.f,0.f,0.f};

#define ITER(kpr, vpr)                                                      \
  do {                                                                      \
    short4v ke = __builtin_shufflevector(kpr, kpr, 0,1,2,3);                \
    short4v ko = __builtin_shufflevector(kpr, kpr, 4,5,6,7);                \
    float4v zero = {0.f,0.f,0.f,0.f};                                       \
    __builtin_amdgcn_s_setprio(1);                                          \
    float4v s0e = __builtin_amdgcn_mfma_f32_16x16x16bf16_1k(ke, qf0, zero, 0,0,0); \
    float4v s0o = __builtin_amdgcn_mfma_f32_16x16x16bf16_1k(ko, qf0, zero, 0,0,0); \
    float4v s1e = __builtin_amdgcn_mfma_f32_16x16x16bf16_1k(ke, qf1, zero, 0,0,0); \
    float4v s1o = __builtin_amdgcn_mfma_f32_16x16x16bf16_1k(ko, qf1, zero, 0,0,0); \
    float p0e0 = fast_exp2(s0e[0]), p0e1 = fast_exp2(s0e[1]);               \
    float p0e2 = fast_exp2(s0e[2]), p0e3 = fast_exp2(s0e[3]);               \
    float p0o0 = fast_exp2(s0o[0]), p0o1 = fast_exp2(s0o[1]);               \
    float p0o2 = fast_exp2(s0o[2]), p0o3 = fast_exp2(s0o[3]);               \
    float p1e0 = fast_exp2(s1e[0]), p1e1 = fast_exp2(s1e[1]);               \
    float p1e2 = fast_exp2(s1e[2]), p1e3 = fast_exp2(s1e[3]);               \
    float p1o0 = fast_exp2(s1o[0]), p1o1 = fast_exp2(s1o[1]);               \
    float p1o2 = fast_exp2(s1o[2]), p1o3 = fast_exp2(s1o[3]);               \
    short4v pb0e = pack4_bf16(p0e0, p0e1, p0e2, p0e3);                      \
    short4v pb0o = pack4_bf16(p0o0, p0o1, p0o2, p0o3);                      \
    short4v pb1e = pack4_bf16(p1e0, p1e1, p1e2, p1e3);                      \
    short4v pb1o = pack4_bf16(p1o0, p1o1, p1o2, p1o3);                      \
    short8v pb0 = __builtin_shufflevector(pb0e, pb0o, 0,1,2,3,4,5,6,7);     \
    short8v pb1 = __builtin_shufflevector(pb1e, pb1o, 0,1,2,3,4,5,6,7);     \
    a0   = __builtin_amdgcn_mfma_f32_16x16x32_bf16(vpr, pb0, a0,   0,0,0);  \
    a1   = __builtin_amdgcn_mfma_f32_16x16x32_bf16(vpr, pb1, a1,   0,0,0);  \
    lac0 = __builtin_amdgcn_mfma_f32_16x16x32_bf16(ones8, pb0, lac0, 0,0,0);\
    lac1 = __builtin_amdgcn_mfma_f32_16x16x32_bf16(ones8, pb1, lac1, 0,0,0);\
    __builtin_amdgcn_s_setprio(0);                                          \
  } while (0)

  // prologue: pair-fragments for iters 0 (A) and 1 (B)
  short8v kA = *(const short8v*)(kp16);
  short8v vA = *(const short8v*)(vp16);
  short8v kB = *(const short8v*)(kp16 + 512);
  short8v vB = *(const short8v*)(vp16 + 512);

  #pragma unroll 4
  for (int it2 = 0; it2 < PITERS/2; ++it2) {
    // prefetch iters 2*it2+2 (A') and 2*it2+3 (B'); benign ws over-read at tail
    int oA = (2*it2 + 2) * 512;
    int oB = (2*it2 + 3) * 512;
    short8v nkA = *(const short8v*)(kp16 + oA);
    short8v nvA = *(const short8v*)(vp16 + oA);
    short8v nkB = *(const short8v*)(kp16 + oB);
    short8v nvB = *(const short8v*)(vp16 + oB);

    ITER(kA, vA);
    ITER(kB, vB);

    kA = nkA; vA = nvA; kB = nkB; vB = nvB;
  }
#undef ITER

  // per-wave partials: a0/a1 rows, lac[0] = full per-quarter l for q=l&15
  float l0 = lac0[0], l1 = lac1[0];

  // combine the 4 quarters: waves 1..3 publish, wave 0 reduces + stores
  if (quart != 0) {
    float* cp = &comb[quart-1][lane][0];
    cp[0] = a0[0]; cp[1] = a0[1]; cp[2] = a0[2]; cp[3] = a0[3];
    cp[4] = a1[0]; cp[5] = a1[1]; cp[6] = a1[2]; cp[7] = a1[3];
    cp[8] = l0;    cp[9] = l1;
  }
  __syncthreads();
  if (quart == 0) {
    float o0[4], o1[4];
    #pragma unroll
    for (int r = 0; r < 4; ++r) { o0[r] = a0[r]; o1[r] = a1[r]; }
    #pragma unroll
    for (int wv = 0; wv < 3; ++wv) {
      const float* cp = &comb[wv][lane][0];
      o0[0] += cp[0]; o0[1] += cp[1]; o0[2] += cp[2]; o0[3] += cp[3];
      o1[0] += cp[4]; o1[1] += cp[5]; o1[2] += cp[6]; o1[3] += cp[7];
      l0 += cp[8];    l1 += cp[9];
    }
    float inv0 = 1.0f / l0, inv1 = 1.0f / l1;

    int b = bh >> 2, h = bh & 3;
    float* ob = out + ((size_t)(b*64 + h*16 + g4)) * NTOK;
    #pragma unroll
    for (int r = 0; r < 4; ++r) {
      ob[(size_t)r*NTOK + qbase      + lr] = o0[r] * inv0;
      ob[(size_t)r*NTOK + qbase + 16 + lr] = o1[r] * inv1;
    }
  }
}

extern "C" void kernel_launch(void* const* d_in, const int* in_sizes, int n_in,
                              void* d_out, int out_size, void* d_ws, size_t ws_size,
                              hipStream_t stream) {
  const float* x    = (const float*)d_in[0];   // (2,64,64,64)
  const float* w    = (const float*)d_in[1];   // (192,64)
  const float* bias = (const float*)d_in[2];   // (192,)
  float* out  = (float*)d_out;                 // (2,64,64,64)
  ushort* wsu = (ushort*)d_ws;                 // 3 MB used (+~2KB over-read pad)

  qkv_proj <<<1536, 256, 0, stream>>>(x, w, bias, wsu);
  attn_mfma<<<1024, 256, 0, stream>>>(wsu, out);
}